// Round 1
// baseline (17628.755 us; speedup 1.0000x reference)
//
#include <hip/hip_runtime.h>
#include <hip/hip_cooperative_groups.h>

namespace cg = cooperative_groups;

typedef unsigned short u16;
typedef short short8 __attribute__((ext_vector_type(8)));
typedef float f32x4 __attribute__((ext_vector_type(4)));

static constexpr int T = 512, B = 128, D = 512, H = 512;

// ---- workspace layout (bytes) ----
// W packed bf16, MFMA-B blocked layout: [32 colgrp][128 kb][48 n][8 k] = 3,145,728 B
static constexpr size_t WS_WPACK = 0;
static constexpr size_t WS_MASK  = 3145728;            // float[512][128] (1.0 = keep, 0.0 = reset)
static constexpr size_t WS_HBF   = WS_MASK + 262144;   // u16[2][128][512] bf16 h, pre-masked for next step
// total ~3.67 MB

__device__ __forceinline__ u16 f2bf(float f) {
  unsigned b = __float_as_uint(f);
  b = (b + 0x7FFFu + ((b >> 16) & 1u)) >> 16;  // RN-even
  return (u16)b;
}

// Pack Wi[512,1536], Wh_rz[512,1024], Wh_n[512,512] (fp32) into bf16 blocked
// B-fragment layout: wpack[cg][kb][n][i] = W[k=kb*8+i][gate g=n>>4, col j=cg*16+(n&15)]
// k<512 rows are the x-projection (Wi), k>=512 the recurrent part.
__global__ void pack_w_kernel(const float* __restrict__ Wi,
                              const float* __restrict__ Whrz,
                              const float* __restrict__ Whn,
                              u16* __restrict__ wpack) {
  int c = blockIdx.x * 256 + threadIdx.x;       // cell = ((cg*128)+kb)*48+n
  if (c >= 32 * 128 * 48) return;
  int n  = c % 48;
  int kb = (c / 48) % 128;
  int cgrp = c / (48 * 128);
  int g = n >> 4, jl = n & 15;
  int j = cgrp * 16 + jl;
  u16 tmp[8] __attribute__((aligned(16)));
#pragma unroll
  for (int i = 0; i < 8; ++i) {
    int k = kb * 8 + i;
    float v;
    if (k < 512) {
      v = Wi[k * 1536 + g * 512 + j];
    } else {
      int kh = k - 512;
      v = (g == 0) ? Whrz[kh * 1024 + j]
        : (g == 1) ? Whrz[kh * 1024 + 512 + j]
                   : Whn[kh * 512 + j];
    }
    tmp[i] = f2bf(v);
  }
  *reinterpret_cast<uint4*>(wpack + (size_t)c * 8) = *reinterpret_cast<const uint4*>(tmp);
}

// Detect resets dtype (u8 bool / int32 / fp32), build fp32 keep-mask [T][B],
// and init h bf16 buffer 0 = bf16(h0 * mask[0]).
__global__ void init_kernel(const void* __restrict__ resets_raw,
                            const float* __restrict__ h0,
                            float* __restrict__ mask,
                            u16* __restrict__ hbf) {
  __shared__ int s_flags;
  if (threadIdx.x == 0) s_flags = 0;
  __syncthreads();
  const unsigned char* u8 = (const unsigned char*)resets_raw;
  {
    int p = threadIdx.x * 4;                     // scan first 1 KB
    int f = 0;
    if (u8[p + 1] | u8[p + 2]) f |= 1;           // nonzero off-word bytes -> not int32
    unsigned char b3 = u8[p + 3];
    if (b3 == 0x3F) f |= 2;                      // 1.0f high byte -> fp32
    else if (b3) f |= 1;
    if (f) atomicOr(&s_flags, f);
  }
  __syncthreads();
  int flags = s_flags;
  int idx = blockIdx.x * 256 + threadIdx.x;      // 0..65535
  bool rv;
  if (flags & 2)      rv = ((const float*)resets_raw)[idx] != 0.0f;
  else if (flags & 1) rv = u8[idx] != 0;
  else                rv = ((const int*)resets_raw)[idx] != 0;
  mask[idx] = rv ? 0.0f : 1.0f;
  int b = idx >> 9;                              // for h init: idx = b*512+j
  bool r0;
  if (flags & 2)      r0 = ((const float*)resets_raw)[b] != 0.0f;
  else if (flags & 1) r0 = u8[b] != 0;
  else                r0 = ((const int*)resets_raw)[b] != 0;
  float h = r0 ? 0.0f : h0[idx];
  hbf[idx] = f2bf(h);                            // buffer 0, pre-masked with mask[0]
}

// Persistent cooperative scan. Grid 256 = 8 row-groups(16 batch) x 32 col-groups(16 h-cols).
// Per block LDS: W slice 96KB (resident all steps) + A staging 32KB + gate exchange 4KB.
// Waves: 0=r gate (full K), 1=z gate (full K), 2=xn (x half), 3=hn (h half).
__launch_bounds__(256, 1)
__global__ void scan_kernel(const float* __restrict__ ins,
                            const float* __restrict__ h0,
                            const float* __restrict__ bi,
                            const float* __restrict__ bhn,
                            const u16* __restrict__ wpack,
                            const float* __restrict__ mask,
                            u16* __restrict__ hbf,
                            float* __restrict__ out) {
  cg::grid_group grid = cg::this_grid();
  extern __shared__ char smem[];
  u16*   w_lds = (u16*)smem;                         // [128 kb][48 n][8]  = 96 KB
  u16*   a_lds = (u16*)(smem + 98304);               // [128 kb][16 m][8]  = 32 KB
  float* o_lds = (float*)(smem + 98304 + 32768);     // [4 gate][16][16]   =  4 KB

  const int tid  = threadIdx.x;
  const int cgi  = blockIdx.x & 31;    // column group
  const int rg   = blockIdx.x >> 5;    // row (batch) group
  const int lane = tid & 63;
  const int wv   = tid >> 6;

  { // one-time W slice load: straight 16B copy, coalesced
    const u16* src = wpack + (size_t)cgi * (128 * 48 * 8);
    for (int o = tid; o < 128 * 48; o += 256)
      *reinterpret_cast<uint4*>(w_lds + o * 8) = *reinterpret_cast<const uint4*>(src + o * 8);
  }

  const int m_s = tid & 15;            // staging: row within group
  const int g_s = tid >> 4;            // staging: kb sub-index 0..15
  const int quad = lane >> 4;
  const int lm = lane & 15;
  const int nb  = (wv == 3) ? 32 : wv * 16;   // B-tile column base
  const int kk0 = (wv == 3) ? 16 : 0;         // wave 3: h half only
  const int kk1 = (wv == 2) ? 16 : 32;        // wave 2: x half only

  const int b_l = tid >> 4, j_l = tid & 15;   // epilogue cell
  const int b_g = rg * 16 + b_l;
  const int j_g = cgi * 16 + j_l;
  const float bi_r = bi[j_g], bi_z = bi[512 + j_g], bi_n = bi[1024 + j_g];
  const float bh_nv = bhn[j_g];

  float* ys = out + (size_t)B * H;     // output 0 is hT, then ys[T][B][H]
  const int xrow = rg * 16 + m_s;

  for (int t = 0; t < T; ++t) {
    const int buf = t & 1;
    // ---- stage x_t slice -> a_lds kb 0..63 (fp32 -> bf16) ----
#pragma unroll
    for (int it = 0; it < 4; ++it) {
      int kb = it * 16 + g_s;
      const float* s = ins + ((size_t)t * B + xrow) * D + kb * 8;
      float4 f0 = *reinterpret_cast<const float4*>(s);
      float4 f1 = *reinterpret_cast<const float4*>(s + 4);
      u16 tmp[8] __attribute__((aligned(16)));
      tmp[0] = f2bf(f0.x); tmp[1] = f2bf(f0.y); tmp[2] = f2bf(f0.z); tmp[3] = f2bf(f0.w);
      tmp[4] = f2bf(f1.x); tmp[5] = f2bf(f1.y); tmp[6] = f2bf(f1.z); tmp[7] = f2bf(f1.w);
      *reinterpret_cast<uint4*>(a_lds + (kb * 16 + m_s) * 8) = *reinterpret_cast<const uint4*>(tmp);
    }
    // ---- stage h slice (already bf16, already reset-masked) -> kb 64..127 ----
#pragma unroll
    for (int it = 0; it < 4; ++it) {
      int kb = it * 16 + g_s;
      const u16* s = hbf + ((size_t)buf * B + xrow) * H + kb * 8;
      *reinterpret_cast<uint4*>(a_lds + ((64 + kb) * 16 + m_s) * 8) = *reinterpret_cast<const uint4*>(s);
    }
    __syncthreads();

    // ---- per-wave MFMA 16x16 tile ----
    f32x4 acc = {0.f, 0.f, 0.f, 0.f};
    for (int kk = kk0; kk < kk1; ++kk) {
      int kb = kk * 4 + quad;
      short8 av = *reinterpret_cast<const short8*>(a_lds + (kb * 16 + lm) * 8);
      short8 bv = *reinterpret_cast<const short8*>(w_lds + (kb * 48 + nb + lm) * 8);
      acc = __builtin_amdgcn_mfma_f32_16x16x32_bf16(av, bv, acc, 0, 0, 0);
    }
#pragma unroll
    for (int r = 0; r < 4; ++r)                    // C/D layout: row=quad*4+r, col=lane&15
      o_lds[wv * 256 + (quad * 4 + r) * 16 + lm] = acc[r];
    __syncthreads();

    // ---- gate epilogue: one thread per (batch, col) cell ----
    float racc = o_lds[          b_l * 16 + j_l] + bi_r;
    float zacc = o_lds[256     + b_l * 16 + j_l] + bi_z;
    float xnv  = o_lds[2 * 256 + b_l * 16 + j_l] + bi_n;
    float hnv  = o_lds[3 * 256 + b_l * 16 + j_l] + bh_nv;
    float mcur = mask[t * B + b_g];
    float hprev = (t == 0 ? h0[b_g * H + j_g]
                          : ys[((size_t)(t - 1) * B + b_g) * H + j_g]) * mcur;
    float rr = 1.0f / (1.0f + __expf(-racc));
    float zz = 1.0f / (1.0f + __expf(-zacc));
    float nn = tanhf(xnv + rr * hnv);
    float hnew = (1.0f - zz) * nn + zz * hprev;
    ys[((size_t)t * B + b_g) * H + j_g] = hnew;    // fp32 master state lives in ys
    float mnext = (t < T - 1) ? mask[(t + 1) * B + b_g] : 1.0f;
    hbf[((size_t)(1 - buf) * B + b_g) * H + j_g] = f2bf(hnew * mnext);  // pre-masked for t+1
    if (t == T - 1) out[b_g * H + j_g] = hnew;     // hT
    grid.sync();
  }
}

extern "C" void kernel_launch(void* const* d_in, const int* in_sizes, int n_in,
                              void* d_out, int out_size, void* d_ws, size_t ws_size,
                              hipStream_t stream) {
  const float* ins  = (const float*)d_in[0];
  const void*  rst  = d_in[1];
  const float* h0   = (const float*)d_in[2];
  const float* Wi   = (const float*)d_in[3];
  const float* bi   = (const float*)d_in[4];
  const float* Whrz = (const float*)d_in[5];
  const float* Whn  = (const float*)d_in[6];
  const float* bhn  = (const float*)d_in[7];

  char* ws = (char*)d_ws;
  u16*   wpack = (u16*)(ws + WS_WPACK);
  float* mask  = (float*)(ws + WS_MASK);
  u16*   hbf   = (u16*)(ws + WS_HBF);
  float* out   = (float*)d_out;

  hipLaunchKernelGGL(pack_w_kernel, dim3(768), dim3(256), 0, stream, Wi, Whrz, Whn, wpack);
  hipLaunchKernelGGL(init_kernel, dim3(256), dim3(256), 0, stream, rst, h0, mask, hbf);

  (void)hipFuncSetAttribute((const void*)scan_kernel,
                            hipFuncAttributeMaxDynamicSharedMemorySize, 135168);
  void* args[8];
  args[0] = (void*)&ins;   args[1] = (void*)&h0;   args[2] = (void*)&bi;  args[3] = (void*)&bhn;
  args[4] = (void*)&wpack; args[5] = (void*)&mask; args[6] = (void*)&hbf; args[7] = (void*)&out;
  (void)hipLaunchCooperativeKernel((const void*)scan_kernel, dim3(256), dim3(256),
                                   args, 135168, stream);
}

// Round 2
// 4106.361 us; speedup vs baseline: 4.2930x; 4.2930x over previous
//
#include <hip/hip_runtime.h>

typedef unsigned short u16;
typedef unsigned int u32;
typedef unsigned long long u64;
typedef short short8 __attribute__((ext_vector_type(8)));
typedef float f32x4 __attribute__((ext_vector_type(4)));

static constexpr int T = 512, B = 128, D = 512, H = 512;

// ---- workspace layout (bytes) ----
static constexpr size_t WS_WPACK = 0;                    // bf16 W blocked: 3,145,728
static constexpr size_t WS_MASK  = 3145728;              // float[512][128]: 262,144
static constexpr size_t WS_HBF   = WS_MASK + 262144;     // u16[2][128][512]: 262,144
static constexpr size_t WS_FLAGS = WS_HBF + 262144;      // u32[8][32]: 1,024
static constexpr size_t WS_XBF   = WS_FLAGS + 1024;      // optional bf16 ins: 67,108,864

__device__ __forceinline__ u32 f2bf(float f) {
  unsigned b = __float_as_uint(f);
  b = (b + 0x7FFFu + ((b >> 16) & 1u)) >> 16;  // RN-even
  return b & 0xFFFFu;
}

// Pack Wi[512,1536], Wh_rz[512,1024], Wh_n[512,512] (fp32) into bf16 blocked
// B-fragment layout: wpack[cg][kb][n][i] = W[k=kb*8+i][gate g=n>>4, col j=cg*16+(n&15)]
__global__ void pack_w_kernel(const float* __restrict__ Wi,
                              const float* __restrict__ Whrz,
                              const float* __restrict__ Whn,
                              u16* __restrict__ wpack) {
  int c = blockIdx.x * 256 + threadIdx.x;
  if (c >= 32 * 128 * 48) return;
  int n  = c % 48;
  int kb = (c / 48) % 128;
  int cgrp = c / (48 * 128);
  int g = n >> 4, jl = n & 15;
  int j = cgrp * 16 + jl;
  u16 tmp[8] __attribute__((aligned(16)));
#pragma unroll
  for (int i = 0; i < 8; ++i) {
    int k = kb * 8 + i;
    float v;
    if (k < 512) {
      v = Wi[k * 1536 + g * 512 + j];
    } else {
      int kh = k - 512;
      v = (g == 0) ? Whrz[kh * 1024 + j]
        : (g == 1) ? Whrz[kh * 1024 + 512 + j]
                   : Whn[kh * 512 + j];
    }
    tmp[i] = (u16)f2bf(v);
  }
  *reinterpret_cast<uint4*>(wpack + (size_t)c * 8) = *reinterpret_cast<const uint4*>(tmp);
}

// Detect resets dtype, build fp32 keep-mask [T][B], init h bf16 buf 0, zero flags.
__global__ void init_kernel(const void* __restrict__ resets_raw,
                            const float* __restrict__ h0,
                            float* __restrict__ mask,
                            u16* __restrict__ hbf,
                            u32* __restrict__ flags) {
  __shared__ int s_flags;
  if (threadIdx.x == 0) s_flags = 0;
  __syncthreads();
  const unsigned char* u8 = (const unsigned char*)resets_raw;
  {
    int p = threadIdx.x * 4;
    int f = 0;
    if (u8[p + 1] | u8[p + 2]) f |= 1;
    unsigned char b3 = u8[p + 3];
    if (b3 == 0x3F) f |= 2;
    else if (b3) f |= 1;
    if (f) atomicOr(&s_flags, f);
  }
  __syncthreads();
  int flags_d = s_flags;
  int idx = blockIdx.x * 256 + threadIdx.x;
  bool rv;
  if (flags_d & 2)      rv = ((const float*)resets_raw)[idx] != 0.0f;
  else if (flags_d & 1) rv = u8[idx] != 0;
  else                  rv = ((const int*)resets_raw)[idx] != 0;
  mask[idx] = rv ? 0.0f : 1.0f;
  int b = idx >> 9;
  bool r0;
  if (flags_d & 2)      r0 = ((const float*)resets_raw)[b] != 0.0f;
  else if (flags_d & 1) r0 = u8[b] != 0;
  else                  r0 = ((const int*)resets_raw)[b] != 0;
  float h = r0 ? 0.0f : h0[idx];
  hbf[idx] = (u16)f2bf(h);                       // buffer 0, pre-masked with mask[0]
  if (blockIdx.x == 0 && threadIdx.x < 256) flags[threadIdx.x] = 0;
}

// Optional pre-pass: ins fp32 -> bf16 (removes per-step conversion bursts).
__global__ void convert_x_kernel(const float* __restrict__ ins, u16* __restrict__ xbf) {
  size_t i = ((size_t)blockIdx.x * 256 + threadIdx.x) * 8;
  float4 f0 = *reinterpret_cast<const float4*>(ins + i);
  float4 f1 = *reinterpret_cast<const float4*>(ins + i + 4);
  u16 tmp[8] __attribute__((aligned(16)));
  tmp[0] = (u16)f2bf(f0.x); tmp[1] = (u16)f2bf(f0.y);
  tmp[2] = (u16)f2bf(f0.z); tmp[3] = (u16)f2bf(f0.w);
  tmp[4] = (u16)f2bf(f1.x); tmp[5] = (u16)f2bf(f1.y);
  tmp[6] = (u16)f2bf(f1.z); tmp[7] = (u16)f2bf(f1.w);
  *reinterpret_cast<uint4*>(xbf + i) = *reinterpret_cast<const uint4*>(tmp);
}

// Persistent scan, per-row-group flag barrier (no grid.sync).
// Grid 256: rg = blockIdx&7 (same XCD under round-robin dispatch), cgi = blockIdx>>3.
// Waves: 0=r (full K), 1=z (full K), 2=xn (x half), 3=hn (h half).
// Cross-block h exchange via device-scope atomics (coherence point), so no
// cache-maintenance fences needed; __syncthreads() drains vmcnt(0) so the
// release flag-store is ordered after all threads' coherent h stores.
__launch_bounds__(256, 1)
__global__ void scan_kernel(const float* __restrict__ ins,
                            const u16* __restrict__ xbf,   // may be null
                            const float* __restrict__ h0,
                            const float* __restrict__ bi,
                            const float* __restrict__ bhn,
                            const u16* __restrict__ wpack,
                            const float* __restrict__ mask,
                            u16* __restrict__ hbf,
                            u32* __restrict__ flags,
                            float* __restrict__ out) {
  extern __shared__ char smem[];
  u16*   w_lds = (u16*)smem;                     // [128 kb][48 n][8] = 96 KB
  float* o_lds = (float*)(smem + 98304);         // [4 gate][16][16]  =  4 KB

  const int tid  = threadIdx.x;
  const int rg   = blockIdx.x & 7;
  const int cgi  = blockIdx.x >> 3;
  const int lane = tid & 63;
  const int wv   = tid >> 6;
  const int quad = lane >> 4;
  const int lm   = lane & 15;

  { // one-time W slice load
    const u16* src = wpack + (size_t)cgi * (128 * 48 * 8);
    for (int o = tid; o < 128 * 48; o += 256)
      *reinterpret_cast<uint4*>(w_lds + o * 8) = *reinterpret_cast<const uint4*>(src + o * 8);
  }

  const int nb  = (wv == 3) ? 32 : wv * 16;      // B-tile gate-column base
  const int row = rg * 16 + lm;                  // A-fragment source row
  const int b_l = tid >> 4, j_l = tid & 15;
  const int b_g = rg * 16 + b_l;
  const int j_g = cgi * 16 + j_l;
  const float bi_r = bi[j_g], bi_z = bi[512 + j_g], bi_n = bi[1024 + j_g];
  const float bh_nv = bhn[j_g];
  float* ys = out + (size_t)B * H;

  float hprev = h0[b_g * H + j_g];               // fp32 master state in register
  float mcur  = mask[b_g];

  const u64* hbf64 = (const u64*)hbf;
  u32*       hbf32 = (u32*)hbf;

  __syncthreads();                               // W resident

  for (int t = 0; t < T; ++t) {
    const int buf = t & 1;
    f32x4 acc = {0.f, 0.f, 0.f, 0.f};

    // ---- x-half MFMAs (independent of h; overlaps barrier latency) ----
    if (wv != 3) {
      if (xbf) {
        const u16* xs = xbf + ((size_t)t * B + row) * D;
#pragma unroll
        for (int kk = 0; kk < 16; ++kk) {
          int kb = kk * 4 + quad;
          short8 av = *reinterpret_cast<const short8*>(xs + kb * 8);
          short8 bv = *reinterpret_cast<const short8*>(w_lds + (kb * 48 + nb + lm) * 8);
          acc = __builtin_amdgcn_mfma_f32_16x16x32_bf16(av, bv, acc, 0, 0, 0);
        }
      } else {
        const float* xs = ins + ((size_t)t * B + row) * D;
#pragma unroll
        for (int kk = 0; kk < 16; ++kk) {
          int kb = kk * 4 + quad;
          float4 f0 = *reinterpret_cast<const float4*>(xs + kb * 8);
          float4 f1 = *reinterpret_cast<const float4*>(xs + kb * 8 + 4);
          u16 tmp[8] __attribute__((aligned(16)));
          tmp[0] = (u16)f2bf(f0.x); tmp[1] = (u16)f2bf(f0.y);
          tmp[2] = (u16)f2bf(f0.z); tmp[3] = (u16)f2bf(f0.w);
          tmp[4] = (u16)f2bf(f1.x); tmp[5] = (u16)f2bf(f1.y);
          tmp[6] = (u16)f2bf(f1.z); tmp[7] = (u16)f2bf(f1.w);
          short8 av = *reinterpret_cast<const short8*>(tmp);
          short8 bv = *reinterpret_cast<const short8*>(w_lds + (kb * 48 + nb + lm) * 8);
          acc = __builtin_amdgcn_mfma_f32_16x16x32_bf16(av, bv, acc, 0, 0, 0);
        }
      }
    }

    // ---- wait for h(t): peers in this row group published flag >= t ----
    if (t) {
      const u32* fp = flags + rg * 32 + (lane & 31);
      while (true) {
        u32 f = __hip_atomic_load(fp, __ATOMIC_RELAXED, __HIP_MEMORY_SCOPE_AGENT);
        if (__all((int)(f >= (u32)t))) break;
      }
    }

    // ---- h-half MFMAs: A-fragments direct from coherence point ----
    if (wv != 2) {
      const size_t hb = ((size_t)buf * B + row) * 128;   // u64 units (H*2B/8)
#pragma unroll
      for (int kk = 16; kk < 32; ++kk) {
        int kb = kk * 4 + quad;
        union { u64 d[2]; short8 v; } hu;
        const u64* hp = hbf64 + hb + (size_t)(kb - 64) * 2;
        hu.d[0] = __hip_atomic_load(hp,     __ATOMIC_RELAXED, __HIP_MEMORY_SCOPE_AGENT);
        hu.d[1] = __hip_atomic_load(hp + 1, __ATOMIC_RELAXED, __HIP_MEMORY_SCOPE_AGENT);
        short8 bv = *reinterpret_cast<const short8*>(w_lds + (kb * 48 + nb + lm) * 8);
        acc = __builtin_amdgcn_mfma_f32_16x16x32_bf16(hu.v, bv, acc, 0, 0, 0);
      }
    }
#pragma unroll
    for (int r = 0; r < 4; ++r)                  // C/D: row=quad*4+r, col=lm
      o_lds[wv * 256 + (quad * 4 + r) * 16 + lm] = acc[r];
    __syncthreads();

    // ---- gate epilogue: thread owns cell (b_g, j_g) ----
    float racc = o_lds[      b_l * 16 + j_l] + bi_r;
    float zacc = o_lds[256 + b_l * 16 + j_l] + bi_z;
    float xnv  = o_lds[512 + b_l * 16 + j_l] + bi_n;
    float hnv  = o_lds[768 + b_l * 16 + j_l] + bh_nv;
    float hp = hprev * mcur;
    float rr = 1.0f / (1.0f + __expf(-racc));
    float zz = 1.0f / (1.0f + __expf(-zacc));
    float nn = tanhf(xnv + rr * hnv);
    float hnew = (1.0f - zz) * nn + zz * hp;
    ys[((size_t)t * B + b_g) * H + j_g] = hnew;
    float mnext = (t < T - 1) ? mask[(t + 1) * B + b_g] : 1.0f;
    u32 mybf  = f2bf(hnew * mnext);              // pre-masked for t+1
    u32 other = (u32)__shfl_xor((int)mybf, 1);
    if (!(j_l & 1)) {
      u32 packed = mybf | (other << 16);
      __hip_atomic_store(hbf32 + ((size_t)(1 - buf) * B + b_g) * 256 + (j_g >> 1),
                         packed, __ATOMIC_RELAXED, __HIP_MEMORY_SCOPE_AGENT);
    }
    if (t == T - 1) out[b_g * H + j_g] = hnew;
    hprev = hnew; mcur = mnext;
    __syncthreads();                             // drains vmcnt(0): h stores visible
    if (t < T - 1 && tid == 0)
      __hip_atomic_store(flags + rg * 32 + cgi, (u32)(t + 1),
                         __ATOMIC_RELEASE, __HIP_MEMORY_SCOPE_AGENT);
  }
}

extern "C" void kernel_launch(void* const* d_in, const int* in_sizes, int n_in,
                              void* d_out, int out_size, void* d_ws, size_t ws_size,
                              hipStream_t stream) {
  const float* ins  = (const float*)d_in[0];
  const void*  rst  = d_in[1];
  const float* h0   = (const float*)d_in[2];
  const float* Wi   = (const float*)d_in[3];
  const float* bi   = (const float*)d_in[4];
  const float* Whrz = (const float*)d_in[5];
  const float* Whn  = (const float*)d_in[6];
  const float* bhn  = (const float*)d_in[7];

  char* ws = (char*)d_ws;
  u16*   wpack = (u16*)(ws + WS_WPACK);
  float* mask  = (float*)(ws + WS_MASK);
  u16*   hbf   = (u16*)(ws + WS_HBF);
  u32*   flags = (u32*)(ws + WS_FLAGS);
  float* out   = (float*)d_out;

  bool big = ws_size >= WS_XBF + (size_t)T * B * D * 2;
  const u16* xbf = big ? (const u16*)(ws + WS_XBF) : nullptr;

  hipLaunchKernelGGL(pack_w_kernel, dim3(768), dim3(256), 0, stream, Wi, Whrz, Whn, wpack);
  hipLaunchKernelGGL(init_kernel, dim3(256), dim3(256), 0, stream, rst, h0, mask, hbf, flags);
  if (big)
    hipLaunchKernelGGL(convert_x_kernel, dim3(16384), dim3(256), 0, stream,
                       ins, (u16*)(ws + WS_XBF));

  (void)hipFuncSetAttribute((const void*)scan_kernel,
                            hipFuncAttributeMaxDynamicSharedMemorySize, 102400);
  void* args[10];
  args[0] = (void*)&ins;   args[1] = (void*)&xbf;  args[2] = (void*)&h0;
  args[3] = (void*)&bi;    args[4] = (void*)&bhn;  args[5] = (void*)&wpack;
  args[6] = (void*)&mask;  args[7] = (void*)&hbf;  args[8] = (void*)&flags;
  args[9] = (void*)&out;
  (void)hipLaunchCooperativeKernel((const void*)scan_kernel, dim3(256), dim3(256),
                                   args, 102400, stream);
}